// Round 1
// baseline (830.096 us; speedup 1.0000x reference)
//
#include <hip/hip_runtime.h>
#include <stdint.h>

#define N_NODES_C 100000
#define N_PAIRS_C 1600000
#define FDIM 64
#define HH 4
#define DD 16

// ---------------- Phase 1: per-head QKV projection ----------------
// q[n,h,e] = sum_d x[n, h*16+d] * Wq[h,d,e]   (same for k, v)
// One thread per (n, h): reads 16 x-values, writes 16 q + 16 k + 16 v.
__global__ __launch_bounds__(256) void qkv_kernel(
    const float* __restrict__ x,    // (N, 64)
    const float* __restrict__ Wq,   // (4, 16, 16)
    const float* __restrict__ Wk,
    const float* __restrict__ Wv,
    float* __restrict__ q,          // (N, 64) laid out [n][h*16+e]
    float* __restrict__ k,
    float* __restrict__ v)
{
    __shared__ float sWq[HH * DD * DD];
    __shared__ float sWk[HH * DD * DD];
    __shared__ float sWv[HH * DD * DD];
    for (int t = threadIdx.x; t < HH * DD * DD; t += 256) {
        sWq[t] = Wq[t];
        sWk[t] = Wk[t];
        sWv[t] = Wv[t];
    }
    __syncthreads();

    int gid = blockIdx.x * 256 + threadIdx.x;
    int n = gid >> 2;
    int h = gid & 3;
    if (n >= N_NODES_C) return;

    const float* xp = x + (int64_t)n * FDIM + h * DD;
    float xr[DD];
#pragma unroll
    for (int d0 = 0; d0 < DD; d0 += 4) {
        float4 t4 = *reinterpret_cast<const float4*>(xp + d0);
        xr[d0 + 0] = t4.x; xr[d0 + 1] = t4.y; xr[d0 + 2] = t4.z; xr[d0 + 3] = t4.w;
    }

    float qo[DD], ko[DD], vo[DD];
#pragma unroll
    for (int e = 0; e < DD; e++) { qo[e] = 0.f; ko[e] = 0.f; vo[e] = 0.f; }

    const float* wqh = sWq + h * DD * DD;
    const float* wkh = sWk + h * DD * DD;
    const float* wvh = sWv + h * DD * DD;
#pragma unroll
    for (int d = 0; d < DD; d++) {
        float xv = xr[d];
#pragma unroll
        for (int e = 0; e < DD; e++) {
            qo[e] = fmaf(xv, wqh[d * DD + e], qo[e]);
            ko[e] = fmaf(xv, wkh[d * DD + e], ko[e]);
            vo[e] = fmaf(xv, wvh[d * DD + e], vo[e]);
        }
    }

    int64_t base = (int64_t)n * FDIM + h * DD;
#pragma unroll
    for (int e0 = 0; e0 < DD; e0 += 4) {
        *reinterpret_cast<float4*>(q + base + e0) = make_float4(qo[e0], qo[e0+1], qo[e0+2], qo[e0+3]);
        *reinterpret_cast<float4*>(k + base + e0) = make_float4(ko[e0], ko[e0+1], ko[e0+2], ko[e0+3]);
        *reinterpret_cast<float4*>(v + base + e0) = make_float4(vo[e0], vo[e0+1], vo[e0+2], vo[e0+3]);
    }
}

// ---------------- Phase 2: per-pair attention + segmented scatter ----------------
// One wave per contiguous chunk of pairs. Lane l -> (h = l>>4, e = l&15).
// idx_i is sorted, so we keep a register accumulator per lane and only
// atomicAdd when the segment (node i) changes.
__global__ __launch_bounds__(256) void pair_kernel(
    const float* __restrict__ q,
    const float* __restrict__ k,
    const float* __restrict__ v,
    const float* __restrict__ w_ij,   // (P, 64)
    const float* __restrict__ phi,    // (P,)
    const float* __restrict__ mask,   // (P,)
    const int*  __restrict__ idx_i,   // (P,)
    const int*  __restrict__ idx_j,   // (P,)
    float* __restrict__ out,          // (N, 64)
    int pairs_per_wave)
{
    int wave = (blockIdx.x * blockDim.x + threadIdx.x) >> 6;
    int lane = threadIdx.x & 63;
    int64_t start = (int64_t)wave * pairs_per_wave;
    if (start >= N_PAIRS_C) return;
    int64_t end = start + pairs_per_wave;
    if (end > N_PAIRS_C) end = N_PAIRS_C;

    float acc = 0.f;
    float qv = 0.f;
    int cur_i = -1;

    for (int64_t p = start; p < end; ++p) {
        int i = idx_i[p];                 // wave-uniform
        if (i != cur_i) {                 // uniform branch
            if (cur_i >= 0) atomicAdd(&out[(int64_t)cur_i * FDIM + lane], acc);
            acc = 0.f;
            cur_i = i;
            qv = q[(int64_t)i * FDIM + lane];
        }
        int j = idx_j[p];                 // wave-uniform
        float wv = w_ij[p * FDIM + lane];
        float kv = k[(int64_t)j * FDIM + lane];
        float vv = v[(int64_t)j * FDIM + lane];
        float s  = phi[p] * mask[p];

        float r = qv * wv * kv;
        // sum across the 16 lanes of this head (xor masks 1,2,4,8 stay in-group)
        r += __shfl_xor(r, 1);
        r += __shfl_xor(r, 2);
        r += __shfl_xor(r, 4);
        r += __shfl_xor(r, 8);
        float alpha = r * 0.25f * s;      // 1/sqrt(D) = 0.25

        acc = fmaf(alpha, vv, acc);
    }
    if (cur_i >= 0) atomicAdd(&out[(int64_t)cur_i * FDIM + lane], acc);
}

extern "C" void kernel_launch(void* const* d_in, const int* in_sizes, int n_in,
                              void* d_out, int out_size, void* d_ws, size_t ws_size,
                              hipStream_t stream) {
    const float* x       = (const float*)d_in[0];
    const float* w_ij    = (const float*)d_in[1];
    const float* phi     = (const float*)d_in[2];
    const float* mask    = (const float*)d_in[3];
    const float* Wq      = (const float*)d_in[4];
    const float* Wk      = (const float*)d_in[5];
    const float* Wv      = (const float*)d_in[6];
    const int*   idx_i   = (const int*)d_in[7];
    const int*   idx_j   = (const int*)d_in[8];
    float* out = (float*)d_out;

    // Workspace: q, k, v tables (N*64 floats each = 25.6 MB each)
    float* q = (float*)d_ws;
    float* k = q + (int64_t)N_NODES_C * FDIM;
    float* v = k + (int64_t)N_NODES_C * FDIM;

    // out is re-poisoned before every timed launch -> zero it (atomics accumulate into it)
    hipMemsetAsync(d_out, 0, (size_t)out_size * sizeof(float), stream);

    // Phase 1
    int qkv_blocks = (N_NODES_C * HH + 255) / 256;
    qkv_kernel<<<qkv_blocks, 256, 0, stream>>>(x, Wq, Wk, Wv, q, k, v);

    // Phase 2: 2048 blocks x 4 waves = 8192 waves
    const int n_waves = 8192;
    int pairs_per_wave = (N_PAIRS_C + n_waves - 1) / n_waves;  // 196
    pair_kernel<<<n_waves / 4, 256, 0, stream>>>(q, k, v, w_ij, phi, mask,
                                                 idx_i, idx_j, out, pairs_per_wave);
}

// Round 2
// 722.985 us; speedup vs baseline: 1.1482x; 1.1482x over previous
//
#include <hip/hip_runtime.h>
#include <stdint.h>

#define N_NODES_C 100000
#define N_PAIRS_C 1600000
#define FDIM 64
#define HH 4
#define DD 16

// ---------------- Phase 1: per-head QKV projection ----------------
// One thread per (n, h). LDS weight blocks padded to stride 264 floats so the
// 4 distinct h-addresses per wave land in different banks (264 % 32 = 8).
__global__ __launch_bounds__(256) void qkv_kernel(
    const float* __restrict__ x,    // (N, 64)
    const float* __restrict__ Wq,   // (4, 16, 16)
    const float* __restrict__ Wk,
    const float* __restrict__ Wv,
    float* __restrict__ q,          // (N, 64)
    float* __restrict__ k,
    float* __restrict__ v)
{
    __shared__ float sWq[HH][DD * DD + 8];
    __shared__ float sWk[HH][DD * DD + 8];
    __shared__ float sWv[HH][DD * DD + 8];
    for (int t = threadIdx.x; t < HH * DD * DD; t += 256) {
        sWq[t >> 8][t & 255] = Wq[t];
        sWk[t >> 8][t & 255] = Wk[t];
        sWv[t >> 8][t & 255] = Wv[t];
    }
    __syncthreads();

    int gid = blockIdx.x * 256 + threadIdx.x;
    int n = gid >> 2;
    int h = gid & 3;
    if (n >= N_NODES_C) return;

    const float* xp = x + (int64_t)n * FDIM + h * DD;
    float xr[DD];
#pragma unroll
    for (int d0 = 0; d0 < DD; d0 += 4) {
        float4 t4 = *reinterpret_cast<const float4*>(xp + d0);
        xr[d0 + 0] = t4.x; xr[d0 + 1] = t4.y; xr[d0 + 2] = t4.z; xr[d0 + 3] = t4.w;
    }

    float qo[DD], ko[DD], vo[DD];
#pragma unroll
    for (int e = 0; e < DD; e++) { qo[e] = 0.f; ko[e] = 0.f; vo[e] = 0.f; }

    const float* wqh = sWq[h];
    const float* wkh = sWk[h];
    const float* wvh = sWv[h];
#pragma unroll
    for (int d = 0; d < DD; d++) {
        float xv = xr[d];
#pragma unroll
        for (int e = 0; e < DD; e++) {
            qo[e] = fmaf(xv, wqh[d * DD + e], qo[e]);
            ko[e] = fmaf(xv, wkh[d * DD + e], ko[e]);
            vo[e] = fmaf(xv, wvh[d * DD + e], vo[e]);
        }
    }

    int64_t base = (int64_t)n * FDIM + h * DD;
#pragma unroll
    for (int e0 = 0; e0 < DD; e0 += 4) {
        *reinterpret_cast<float4*>(q + base + e0) = make_float4(qo[e0], qo[e0+1], qo[e0+2], qo[e0+3]);
        *reinterpret_cast<float4*>(k + base + e0) = make_float4(ko[e0], ko[e0+1], ko[e0+2], ko[e0+3]);
        *reinterpret_cast<float4*>(v + base + e0) = make_float4(vo[e0], vo[e0+1], vo[e0+2], vo[e0+3]);
    }
}

// ---------------- Phase 2: per-pair attention + segmented scatter ----------------
// One 16-lane group per contiguous pair chunk; lane m owns float4 m of the
// 64-float row (head h = m>>2). Depth-2 index prefetch so the j-dependent k/v
// gathers for iteration t+1 issue without waiting on an index load.
__global__ __launch_bounds__(256) void pair_kernel(
    const float* __restrict__ q,
    const float* __restrict__ k,
    const float* __restrict__ v,
    const float* __restrict__ w_ij,   // (P, 64)
    const float* __restrict__ phi,    // (P,)
    const float* __restrict__ mask,   // (P,)
    const int*  __restrict__ idx_i,   // (P,)
    const int*  __restrict__ idx_j,   // (P,)
    float* __restrict__ out,          // (N, 64)
    int pairs_per_group)
{
    int gid = blockIdx.x * 256 + threadIdx.x;
    int grp = gid >> 4;
    int m   = threadIdx.x & 15;

    int64_t start = (int64_t)grp * pairs_per_group;
    if (start >= N_PAIRS_C) return;
    int64_t end = start + pairs_per_group;
    if (end > N_PAIRS_C) end = N_PAIRS_C;

    const float4* w4p = reinterpret_cast<const float4*>(w_ij);
    const float4* q4p = reinterpret_cast<const float4*>(q);
    const float4* k4p = reinterpret_cast<const float4*>(k);
    const float4* v4p = reinterpret_cast<const float4*>(v);

    // ---- pipeline preload: stage A = iteration t, stage B = t+1 ----
    int64_t p1 = (start + 1 < end) ? start + 1 : end - 1;
    int   i_a = idx_i[start];
    int   j_a = idx_j[start];
    float s_a = phi[start] * mask[start];
    int   i_b = idx_i[p1];
    int   j_b = idx_j[p1];
    float s_b = phi[p1] * mask[p1];

    float4 w_a = w4p[start * DD + m];
    float4 k_a = k4p[(int64_t)j_a * DD + m];
    float4 v_a = v4p[(int64_t)j_a * DD + m];

    float4 q4  = q4p[(int64_t)i_a * DD + m];
    int cur_i  = i_a;
    float4 acc = make_float4(0.f, 0.f, 0.f, 0.f);

    for (int64_t p = start; p < end; ++p) {
        // prefetch stage t+2 indices (clamped)
        int64_t p2 = (p + 2 < end) ? p + 2 : end - 1;
        int   i_c = idx_i[p2];
        int   j_c = idx_j[p2];
        float s_c = phi[p2] * mask[p2];

        // stage t+1 payload loads (j_b already resident -> no index wait)
        int64_t pn = (p + 1 < end) ? p + 1 : end - 1;
        float4 w_b = w4p[pn * DD + m];
        float4 k_b = k4p[(int64_t)j_b * DD + m];
        float4 v_b = v4p[(int64_t)j_b * DD + m];

        // ---- compute stage t ----
        if (i_a != cur_i) {            // uniform within the 16-lane group
            int64_t ob = (int64_t)cur_i * FDIM + m * 4;
            atomicAdd(&out[ob + 0], acc.x);
            atomicAdd(&out[ob + 1], acc.y);
            atomicAdd(&out[ob + 2], acc.z);
            atomicAdd(&out[ob + 3], acc.w);
            acc = make_float4(0.f, 0.f, 0.f, 0.f);
            q4 = q4p[(int64_t)i_a * DD + m];
            cur_i = i_a;
        }

        float r = q4.x * w_a.x * k_a.x
                + q4.y * w_a.y * k_a.y
                + q4.z * w_a.z * k_a.z
                + q4.w * w_a.w * k_a.w;
        // reduce across the 4 lanes of this head (lanes 4h..4h+3)
        r += __shfl_xor(r, 1);
        r += __shfl_xor(r, 2);
        float alpha = r * 0.25f * s_a;   // 1/sqrt(16)

        acc.x = fmaf(alpha, v_a.x, acc.x);
        acc.y = fmaf(alpha, v_a.y, acc.y);
        acc.z = fmaf(alpha, v_a.z, acc.z);
        acc.w = fmaf(alpha, v_a.w, acc.w);

        // rotate pipeline
        i_a = i_b; j_a = j_b; s_a = s_b;
        w_a = w_b; k_a = k_b; v_a = v_b;
        i_b = i_c; j_b = j_c; s_b = s_c;
    }

    // final flush
    {
        int64_t ob = (int64_t)cur_i * FDIM + m * 4;
        atomicAdd(&out[ob + 0], acc.x);
        atomicAdd(&out[ob + 1], acc.y);
        atomicAdd(&out[ob + 2], acc.z);
        atomicAdd(&out[ob + 3], acc.w);
    }
}

extern "C" void kernel_launch(void* const* d_in, const int* in_sizes, int n_in,
                              void* d_out, int out_size, void* d_ws, size_t ws_size,
                              hipStream_t stream) {
    const float* x       = (const float*)d_in[0];
    const float* w_ij    = (const float*)d_in[1];
    const float* phi     = (const float*)d_in[2];
    const float* mask    = (const float*)d_in[3];
    const float* Wq      = (const float*)d_in[4];
    const float* Wk      = (const float*)d_in[5];
    const float* Wv      = (const float*)d_in[6];
    const int*   idx_i   = (const int*)d_in[7];
    const int*   idx_j   = (const int*)d_in[8];
    float* out = (float*)d_out;

    float* q = (float*)d_ws;
    float* k = q + (int64_t)N_NODES_C * FDIM;
    float* v = k + (int64_t)N_NODES_C * FDIM;

    hipMemsetAsync(d_out, 0, (size_t)out_size * sizeof(float), stream);

    int qkv_blocks = (N_NODES_C * HH + 255) / 256;
    qkv_kernel<<<qkv_blocks, 256, 0, stream>>>(x, Wq, Wk, Wv, q, k, v);

    // 2048 blocks x 16 groups = 32768 groups, ~49 pairs each
    const int n_groups = 32768;
    int pairs_per_group = (N_PAIRS_C + n_groups - 1) / n_groups;  // 49
    pair_kernel<<<n_groups / 16, 256, 0, stream>>>(q, k, v, w_ij, phi, mask,
                                                   idx_i, idx_j, out, pairs_per_group);
}

// Round 3
// 674.559 us; speedup vs baseline: 1.2306x; 1.0718x over previous
//
#include <hip/hip_runtime.h>
#include <hip/hip_fp16.h>
#include <stdint.h>

#define N_NODES_C 100000
#define N_PAIRS_C 1600000
#define FDIM 64
#define HH 4
#define DD 16

typedef float vf4 __attribute__((ext_vector_type(4)));

// ---------------- Phase 1: per-head QKV projection ----------------
// One thread per (n, h). q table stays fp32 (read rarely, sequentially).
// k,v packed into ONE fp16 table, element-interleaved: kv[n][e*2+0]=k_e,
// kv[n][e*2+1]=v_e  -> pair-phase gathers one 16B load per lane per pair.
__global__ __launch_bounds__(256) void qkv_kernel(
    const float* __restrict__ x,    // (N, 64)
    const float* __restrict__ Wq,   // (4, 16, 16)
    const float* __restrict__ Wk,
    const float* __restrict__ Wv,
    float* __restrict__ q,          // (N, 64) fp32
    __half* __restrict__ kv)        // (N, 128) fp16 interleaved
{
    __shared__ float sWq[HH][DD * DD + 8];
    __shared__ float sWk[HH][DD * DD + 8];
    __shared__ float sWv[HH][DD * DD + 8];
    for (int t = threadIdx.x; t < HH * DD * DD; t += 256) {
        sWq[t >> 8][t & 255] = Wq[t];
        sWk[t >> 8][t & 255] = Wk[t];
        sWv[t >> 8][t & 255] = Wv[t];
    }
    __syncthreads();

    int gid = blockIdx.x * 256 + threadIdx.x;
    int n = gid >> 2;
    int h = gid & 3;
    if (n >= N_NODES_C) return;

    const float* xp = x + (int64_t)n * FDIM + h * DD;
    float xr[DD];
#pragma unroll
    for (int d0 = 0; d0 < DD; d0 += 4) {
        float4 t4 = *reinterpret_cast<const float4*>(xp + d0);
        xr[d0 + 0] = t4.x; xr[d0 + 1] = t4.y; xr[d0 + 2] = t4.z; xr[d0 + 3] = t4.w;
    }

    float qo[DD], ko[DD], vo[DD];
#pragma unroll
    for (int e = 0; e < DD; e++) { qo[e] = 0.f; ko[e] = 0.f; vo[e] = 0.f; }

    const float* wqh = sWq[h];
    const float* wkh = sWk[h];
    const float* wvh = sWv[h];
#pragma unroll
    for (int d = 0; d < DD; d++) {
        float xv = xr[d];
#pragma unroll
        for (int e = 0; e < DD; e++) {
            qo[e] = fmaf(xv, wqh[d * DD + e], qo[e]);
            ko[e] = fmaf(xv, wkh[d * DD + e], ko[e]);
            vo[e] = fmaf(xv, wvh[d * DD + e], vo[e]);
        }
    }

    int64_t qbase = (int64_t)n * FDIM + h * DD;
#pragma unroll
    for (int e0 = 0; e0 < DD; e0 += 4) {
        *reinterpret_cast<float4*>(q + qbase + e0) = make_float4(qo[e0], qo[e0+1], qo[e0+2], qo[e0+3]);
    }

    // interleaved fp16 kv row: 32 halves = 64 B per (n,h), 16B-aligned
    __half2 kvh[DD];
#pragma unroll
    for (int e = 0; e < DD; e++) kvh[e] = __floats2half2_rn(ko[e], vo[e]);
    uint4* dst = reinterpret_cast<uint4*>(kv + (int64_t)n * 128 + h * 32);
    const uint4* src = reinterpret_cast<const uint4*>(kvh);
#pragma unroll
    for (int t = 0; t < 4; t++) dst[t] = src[t];
}

// ---------------- Phase 2: per-pair attention + segmented scatter ----------------
// One 16-lane group per contiguous pair chunk; lane m owns float4 m of the
// 64-float row (head h = m>>2). Depth-2 pipeline on indices + payloads.
// w_ij is a use-once 410 MB stream -> nontemporal so it doesn't evict kv/q.
__global__ __launch_bounds__(256) void pair_kernel(
    const float* __restrict__ q,      // (N, 64) fp32
    const __half* __restrict__ kv,    // (N, 128) fp16 interleaved
    const float* __restrict__ w_ij,   // (P, 64)
    const float* __restrict__ phi,    // (P,)
    const float* __restrict__ mask,   // (P,)
    const int*  __restrict__ idx_i,   // (P,)
    const int*  __restrict__ idx_j,   // (P,)
    float* __restrict__ out,          // (N, 64)
    int pairs_per_group)
{
    int gid = blockIdx.x * 256 + threadIdx.x;
    int grp = gid >> 4;
    int m   = threadIdx.x & 15;

    int64_t start = (int64_t)grp * pairs_per_group;
    if (start >= N_PAIRS_C) return;
    int64_t end = start + pairs_per_group;
    if (end > N_PAIRS_C) end = N_PAIRS_C;

    const vf4*   w4p = reinterpret_cast<const vf4*>(w_ij);
    const float4* q4p = reinterpret_cast<const float4*>(q);

    // ---- pipeline preload: stage A = iteration t, stage B = t+1 ----
    int64_t p1 = (start + 1 < end) ? start + 1 : end - 1;
    int   i_a = idx_i[start];
    int   j_a = idx_j[start];
    float s_a = phi[start] * mask[start];
    int   i_b = idx_i[p1];
    int   j_b = idx_j[p1];
    float s_b = phi[p1] * mask[p1];

    vf4   w_a  = __builtin_nontemporal_load(w4p + start * DD + m);
    uint4 kv_a = *reinterpret_cast<const uint4*>(kv + (int64_t)j_a * 128 + m * 8);

    float4 q4  = q4p[(int64_t)i_a * DD + m];
    int cur_i  = i_a;
    float4 acc = make_float4(0.f, 0.f, 0.f, 0.f);

    for (int64_t p = start; p < end; ++p) {
        // prefetch stage t+2 indices (clamped)
        int64_t p2 = (p + 2 < end) ? p + 2 : end - 1;
        int   i_c = idx_i[p2];
        int   j_c = idx_j[p2];
        float s_c = phi[p2] * mask[p2];

        // stage t+1 payload loads (j_b already resident -> no index wait)
        int64_t pn = (p + 1 < end) ? p + 1 : end - 1;
        vf4   w_b  = __builtin_nontemporal_load(w4p + pn * DD + m);
        uint4 kv_b = *reinterpret_cast<const uint4*>(kv + (int64_t)j_b * 128 + m * 8);

        // ---- compute stage t ----
        if (i_a != cur_i) {            // uniform within the 16-lane group
            int64_t ob = (int64_t)cur_i * FDIM + m * 4;
            atomicAdd(&out[ob + 0], acc.x);
            atomicAdd(&out[ob + 1], acc.y);
            atomicAdd(&out[ob + 2], acc.z);
            atomicAdd(&out[ob + 3], acc.w);
            acc = make_float4(0.f, 0.f, 0.f, 0.f);
            q4 = q4p[(int64_t)i_a * DD + m];
            cur_i = i_a;
        }

        const __half2* hp = reinterpret_cast<const __half2*>(&kv_a);
        float2 e0 = __half22float2(hp[0]);   // (k0, v0)
        float2 e1 = __half22float2(hp[1]);
        float2 e2 = __half22float2(hp[2]);
        float2 e3 = __half22float2(hp[3]);

        float r = q4.x * w_a.x * e0.x
                + q4.y * w_a.y * e1.x
                + q4.z * w_a.z * e2.x
                + q4.w * w_a.w * e3.x;
        // reduce across the 4 lanes of this head (lanes 4h..4h+3)
        r += __shfl_xor(r, 1);
        r += __shfl_xor(r, 2);
        float alpha = r * 0.25f * s_a;   // 1/sqrt(16)

        acc.x = fmaf(alpha, e0.y, acc.x);
        acc.y = fmaf(alpha, e1.y, acc.y);
        acc.z = fmaf(alpha, e2.y, acc.z);
        acc.w = fmaf(alpha, e3.y, acc.w);

        // rotate pipeline
        i_a = i_b; j_a = j_b; s_a = s_b;
        w_a = w_b; kv_a = kv_b;
        i_b = i_c; j_b = j_c; s_b = s_c;
    }

    // final flush
    {
        int64_t ob = (int64_t)cur_i * FDIM + m * 4;
        atomicAdd(&out[ob + 0], acc.x);
        atomicAdd(&out[ob + 1], acc.y);
        atomicAdd(&out[ob + 2], acc.z);
        atomicAdd(&out[ob + 3], acc.w);
    }
}

extern "C" void kernel_launch(void* const* d_in, const int* in_sizes, int n_in,
                              void* d_out, int out_size, void* d_ws, size_t ws_size,
                              hipStream_t stream) {
    const float* x       = (const float*)d_in[0];
    const float* w_ij    = (const float*)d_in[1];
    const float* phi     = (const float*)d_in[2];
    const float* mask    = (const float*)d_in[3];
    const float* Wq      = (const float*)d_in[4];
    const float* Wk      = (const float*)d_in[5];
    const float* Wv      = (const float*)d_in[6];
    const int*   idx_i   = (const int*)d_in[7];
    const int*   idx_j   = (const int*)d_in[8];
    float* out = (float*)d_out;

    float*  q  = (float*)d_ws;                                   // 25.6 MB
    __half* kv = (__half*)(q + (int64_t)N_NODES_C * FDIM);       // 25.6 MB

    hipMemsetAsync(d_out, 0, (size_t)out_size * sizeof(float), stream);

    int qkv_blocks = (N_NODES_C * HH + 255) / 256;
    qkv_kernel<<<qkv_blocks, 256, 0, stream>>>(x, Wq, Wk, Wv, q, kv);

    // 2048 blocks x 16 groups = 32768 groups, ~49 pairs each
    const int n_groups = 32768;
    int pairs_per_group = (N_PAIRS_C + n_groups - 1) / n_groups;  // 49
    pair_kernel<<<n_groups / 16, 256, 0, stream>>>(q, kv, w_ij, phi, mask,
                                                   idx_i, idx_j, out, pairs_per_group);
}